// Round 18
// baseline (78.765 us; speedup 1.0000x reference)
//
#include <hip/hip_runtime.h>

#define NHEADS 8
#define NN     128
#define NCELL  (NN * NN)       // 16384 floats = 64 KiB
#define NT     512             // 8 waves
#define SCALE_F 10.0f

typedef float    nfloat4 __attribute__((ext_vector_type(4)));
typedef _Float16 h4      __attribute__((ext_vector_type(4)));

// Blocked FW, B=16, one block (512 thr)/graph. R14/R16 schedule (61.3us),
// panels stored f16 in LDS (halves DS bytes); dd/diag/closure all f32;
// conversions are transient (convertvector) -- no persistent f16 reg state.
// Thread t: rgrp=t>>4 -> rows 4rgrp..+3 ; cgrp=t&15 -> cols 4cgrp+64c (c=0,1).
// Step kb (2 barriers):  B'(kb) ; bar ; C(kb) + extract(kb+1) + closure(kb+1)
//   [shadow wave kb+1 under setprio(1)] ; bar
//
// LDS: f32 matrix (swizzled) during init/scatter/load; then panels:
//  half-unit offsets:
#define RPO_H  0          // [16][128] R_old  f16
#define RPN_H  2048       // [16][128] R_new  f16
#define CPA_H  4096       // [16][132] C_oldT f16 parity 0
#define CPB_H  6208       // parity 1
//  float-unit offsets (above halves region 8320h = 4160f):
#define DPS_F  4160       // [16][20] diag tile f32
#define RED_F  4480

template<int CBN>   // CBN = 4*(kbn>>2): dd column-half holding block kbn's cols
__device__ __forceinline__ void extract_panels(const float (&dd)[4][8], float* lds,
                                               _Float16* ldsH, const int kbn,
                                               const int t, const int rgrp,
                                               const int cgrp, const int cpH)
{
    if ((rgrp >> 2) == kbn) {                 // wave kbn: row panel + diag
        const int q = rgrp & 3;
        #pragma unroll
        for (int rr = 0; rr < 4; ++rr) {
            const int iloc = 4 * q + rr;
            #pragma unroll
            for (int c = 0; c < 2; ++c) {
                nfloat4 f;
                f.x = dd[rr][c*4+0]; f.y = dd[rr][c*4+1];
                f.z = dd[rr][c*4+2]; f.w = dd[rr][c*4+3];
                *reinterpret_cast<h4*>(ldsH + RPO_H + iloc*128 + (cgrp << 2) + (c << 6)) =
                    __builtin_convertvector(f, h4);
            }
        }
        const int p = cgrp - 4 * (kbn & 3);
        if ((unsigned)p < 4u) {               // diag stays f32 (closure accuracy)
            #pragma unroll
            for (int rr = 0; rr < 4; ++rr) {
                *reinterpret_cast<float4*>(&lds[DPS_F + (4*q+rr) * 20 + (p << 2)]) =
                    make_float4(dd[rr][CBN+0], dd[rr][CBN+1],
                                dd[rr][CBN+2], dd[rr][CBN+3]);
            }
        }
    }
    {
        const int q2 = cgrp - 4 * (kbn & 3);   // col panel -> CPT[m][i] f16
        if ((unsigned)q2 < 4u) {
            #pragma unroll
            for (int e = 0; e < 4; ++e) {
                const int m = 4 * q2 + e;
                nfloat4 f;
                f.x = dd[0][CBN+e]; f.y = dd[1][CBN+e];
                f.z = dd[2][CBN+e]; f.w = dd[3][CBN+e];
                *reinterpret_cast<h4*>(ldsH + cpH + m*132 + (rgrp << 2)) =
                    __builtin_convertvector(f, h4);
            }
        }
    }
}

// wave kbn: f32 in-place shfl closure of DPS (in C's shadow).
__device__ __forceinline__ void closure(float* lds, const int t, const int kbn)
{
    if ((t >> 6) == kbn) {
        asm volatile("s_waitcnt lgkmcnt(0)" ::: "memory");
        const int l  = t & 63;
        const int i  = l & 15;
        const int jq = l >> 4;
        float4 v = *reinterpret_cast<const float4*>(&lds[DPS_F + i*20 + (jq << 2)]);
        float T0 = v.x, T1 = v.y, T2 = v.z, T3 = v.w;
        #pragma unroll
        for (int k = 0; k < 16; ++k) {
            const int ksrc = ((k >> 2) << 4) | i;
            float dik;
            switch (k & 3) {
                case 0: dik = __shfl(T0, ksrc); break;
                case 1: dik = __shfl(T1, ksrc); break;
                case 2: dik = __shfl(T2, ksrc); break;
                default: dik = __shfl(T3, ksrc); break;
            }
            const int rsrc = (jq << 4) | k;
            const float r0 = __shfl(T0, rsrc);
            const float r1 = __shfl(T1, rsrc);
            const float r2 = __shfl(T2, rsrc);
            const float r3 = __shfl(T3, rsrc);
            T0 = fminf(T0, dik + r0);
            T1 = fminf(T1, dik + r1);
            T2 = fminf(T2, dik + r2);
            T3 = fminf(T3, dik + r3);
        }
        *reinterpret_cast<float4*>(&lds[DPS_F + i*20 + (jq << 2)]) =
            make_float4(T0, T1, T2, T3);
    }
}

// B': R_new[r][j] = min_m D*[r][m] + R_old[m][j]; all 512 threads:
// r = t>>5, cols 4*(t&31). R_old f16 (b64 reads), math f32, R_new f16 write.
__device__ __forceinline__ void bprime(float* lds, _Float16* ldsH, const int t)
{
    const float INF = __builtin_huge_valf();
    const int r  = t >> 5;
    const int j4 = (t & 31) << 2;
    float da[16];
    #pragma unroll
    for (int q = 0; q < 4; ++q) {
        float4 d4 = *reinterpret_cast<const float4*>(&lds[DPS_F + r*20 + (q << 2)]);
        da[4*q+0]=d4.x; da[4*q+1]=d4.y; da[4*q+2]=d4.z; da[4*q+3]=d4.w;
    }
    float a0 = INF, a1 = INF, a2 = INF, a3 = INF;
    #pragma unroll
    for (int m = 0; m < 16; ++m) {
        h4 hv = *reinterpret_cast<const h4*>(ldsH + RPO_H + m*128 + j4);
        nfloat4 rv = __builtin_convertvector(hv, nfloat4);
        a0 = fminf(a0, da[m] + rv.x);
        a1 = fminf(a1, da[m] + rv.y);
        a2 = fminf(a2, da[m] + rv.z);
        a3 = fminf(a3, da[m] + rv.w);
    }
    nfloat4 res; res.x = a0; res.y = a1; res.z = a2; res.w = a3;
    *reinterpret_cast<h4*>(ldsH + RPN_H + r*128 + j4) =
        __builtin_convertvector(res, h4);
}

// C: dd = min(dd, C_old[i][m] + R_new[m][j]) over 16 m; panel reads f16.
__device__ __forceinline__ void cphase(float (&dd)[4][8], _Float16* ldsH,
                                       const int rgrp, const int cgrp,
                                       const int cpH)
{
    #pragma unroll
    for (int mq = 0; mq < 4; ++mq) {
        nfloat4 cp[4], ra[4], rb[4];
        #pragma unroll
        for (int e = 0; e < 4; ++e) {
            const int m = 4*mq + e;
            h4 c_ = *reinterpret_cast<const h4*>(ldsH + cpH + m*132 + (rgrp << 2));
            h4 a_ = *reinterpret_cast<const h4*>(ldsH + RPN_H + m*128 + (cgrp << 2));
            h4 b_ = *reinterpret_cast<const h4*>(ldsH + RPN_H + m*128 + (cgrp << 2) + 64);
            cp[e] = __builtin_convertvector(c_, nfloat4);
            ra[e] = __builtin_convertvector(a_, nfloat4);
            rb[e] = __builtin_convertvector(b_, nfloat4);
        }
        #pragma unroll
        for (int e2 = 0; e2 < 2; ++e2) {
            const float c0[4]  = {cp[2*e2].x, cp[2*e2].y, cp[2*e2].z, cp[2*e2].w};
            const float c1[4]  = {cp[2*e2+1].x, cp[2*e2+1].y, cp[2*e2+1].z, cp[2*e2+1].w};
            const float ra0[4] = {ra[2*e2].x, ra[2*e2].y, ra[2*e2].z, ra[2*e2].w};
            const float ra1[4] = {ra[2*e2+1].x, ra[2*e2+1].y, ra[2*e2+1].z, ra[2*e2+1].w};
            const float rb0[4] = {rb[2*e2].x, rb[2*e2].y, rb[2*e2].z, rb[2*e2].w};
            const float rb1[4] = {rb[2*e2+1].x, rb[2*e2+1].y, rb[2*e2+1].z, rb[2*e2+1].w};
            #pragma unroll
            for (int rr = 0; rr < 4; ++rr) {
                #pragma unroll
                for (int e = 0; e < 4; ++e) {
                    dd[rr][e]   = fminf(fminf(dd[rr][e],   c0[rr] + ra0[e]), c1[rr] + ra1[e]);
                    dd[rr][4+e] = fminf(fminf(dd[rr][4+e], c0[rr] + rb0[e]), c1[rr] + rb1[e]);
                }
            }
        }
    }
}

__global__ __launch_bounds__(NT, 2)
void spb_fw_kernel(const int* __restrict__ edge_index,
                   const float* __restrict__ edge_weight,
                   const int num_edges, const int epg,
                   float* __restrict__ out)
{
    __shared__ float lds[NCELL];
    _Float16* const ldsH = reinterpret_cast<_Float16*>(lds);
    const float INF = __builtin_huge_valf();
    const int t    = threadIdx.x;
    const int g    = blockIdx.x;
    const int cgrp = t & 15;
    const int rgrp = t >> 4;

    // ---- prefetch edges (4/thread, clamped; dup scatter idempotent) ----
    const int ebase = g * epg;
    int esrc[4], edst[4]; float ew[4];
    #pragma unroll
    for (int k = 0; k < 4; ++k) {
        int e = t + k * NT;
        e = (e < epg) ? e : (epg - 1);
        const int idx = ebase + e;
        esrc[k] = edge_index[idx];
        edst[k] = edge_index[num_edges + idx];
        ew[k]   = edge_weight[idx];
    }

    // ---- init matrix (swizzled: elem(i,col) at i*128 + (col ^ ((i&7)<<2))) ----
    #pragma unroll
    for (int c = 0; c < 8; ++c) {
        const int m   = t + (c << 9);
        const int i   = m >> 5;
        const int scm = m & 31;
        const int c0  = (scm ^ (i & 7)) << 2;
        float4 v;
        v.x = (c0 + 0 == i) ? 0.0f : INF;
        v.y = (c0 + 1 == i) ? 0.0f : INF;
        v.z = (c0 + 2 == i) ? 0.0f : INF;
        v.w = (c0 + 3 == i) ? 0.0f : INF;
        *reinterpret_cast<float4*>(&lds[m << 2]) = v;
    }
    __syncthreads();

    // ---- scatter edges (atomicMin on int view of positive floats) ----
    #pragma unroll
    for (int k = 0; k < 4; ++k) {
        const int u = esrc[k] - g * NN;
        const int v = edst[k] - g * NN;
        if (u != v && (unsigned)u < (unsigned)NN && (unsigned)v < (unsigned)NN) {
            const int a = (u << 7) + (v ^ ((u & 7) << 2));
            atomicMin(reinterpret_cast<int*>(&lds[a]), __float_as_int(ew[k]));
        }
    }
    __syncthreads();

    // ---- load dd: dd[rr][c*4+e] = d[4rgrp+rr][4cgrp+64c+e] ----
    float dd[4][8];
    #pragma unroll
    for (int rr = 0; rr < 4; ++rr) {
        const int i = (rgrp << 2) + rr;
        const int s = i & 7;
        #pragma unroll
        for (int c = 0; c < 2; ++c) {
            float4 v = *reinterpret_cast<const float4*>(
                &lds[(i << 7) + (((cgrp + 16*c) ^ s) << 2)]);
            dd[rr][c*4+0]=v.x; dd[rr][c*4+1]=v.y; dd[rr][c*4+2]=v.z; dd[rr][c*4+3]=v.w;
        }
    }
    __syncthreads();   // matrix region dead; panels may be written

    // ---- prologue: extract(0) + closure(0) in wave 0's shadow ----
    extract_panels<0>(dd, lds, ldsH, 0, t, rgrp, cgrp, CPA_H);
    closure(lds, t, 0);
    __syncthreads();

    // ---- blocked FW: 8 steps, 2 barriers each (ROLLED) ----
    #pragma unroll 1
    for (int kb = 0; kb < 8; ++kb) {
        bprime(lds, ldsH, t);
        __syncthreads();
        const int kbn = kb + 1;
        const bool shadow = (kb < 7) && ((t >> 6) == kbn);
        if (shadow) __builtin_amdgcn_s_setprio(1);
        cphase(dd, ldsH, rgrp, cgrp, (kb & 1) ? CPB_H : CPA_H);
        if (kb < 7) {
            const int cpH = (kbn & 1) ? CPB_H : CPA_H;
            if (kbn < 4) extract_panels<0>(dd, lds, ldsH, kbn, t, rgrp, cgrp, cpH);
            else         extract_panels<4>(dd, lds, ldsH, kbn, t, rgrp, cgrp, cpH);
            closure(lds, t, kbn);
        }
        if (shadow) __builtin_amdgcn_s_setprio(0);
        __syncthreads();
    }

    // ---- reductions (max finite, global max) ----
    float mF = 0.0f, mA = 0.0f;
    #pragma unroll
    for (int rr = 0; rr < 4; ++rr)
        #pragma unroll
        for (int j = 0; j < 8; ++j) {
            const float v = dd[rr][j];
            mA = fmaxf(mA, v);
            mF = fmaxf(mF, v < INF ? v : 0.0f);
        }
    #pragma unroll
    for (int o = 32; o > 0; o >>= 1) {
        mF = fmaxf(mF, __shfl_xor(mF, o));
        mA = fmaxf(mA, __shfl_xor(mA, o));
    }
    if ((t & 63) == 0) {
        lds[RED_F + ((t >> 6) << 1)]     = mF;
        lds[RED_F + ((t >> 6) << 1) + 1] = mA;
    }
    __syncthreads();
    mF = lds[RED_F]; mA = lds[RED_F + 1];
    #pragma unroll
    for (int wv = 1; wv < 8; ++wv) {
        mF = fmaxf(mF, lds[RED_F + wv*2]);
        mA = fmaxf(mA, lds[RED_F + wv*2 + 1]);
    }
    const float twoF  = 2.0f * mF;
    const float maxv  = fmaxf((mA == INF) ? twoF : mF, 1e-8f);
    const float nscal = -SCALE_F / maxv;

    // ---- normalize in registers, store 8 heads (coalesced, nontemporal) ----
    float* const outg = out + (size_t)g * (NHEADS * NCELL);
    #pragma unroll
    for (int rr = 0; rr < 4; ++rr) {
        const int i = (rgrp << 2) + rr;
        #pragma unroll
        for (int c = 0; c < 2; ++c) {
            nfloat4 v;
            v.x = ((dd[rr][c*4+0] == INF) ? twoF : dd[rr][c*4+0]) * nscal;
            v.y = ((dd[rr][c*4+1] == INF) ? twoF : dd[rr][c*4+1]) * nscal;
            v.z = ((dd[rr][c*4+2] == INF) ? twoF : dd[rr][c*4+2]) * nscal;
            v.w = ((dd[rr][c*4+3] == INF) ? twoF : dd[rr][c*4+3]) * nscal;
            const int o = (i << 7) + (cgrp << 2) + (c << 6);
            #pragma unroll
            for (int h = 0; h < NHEADS; ++h) {
                __builtin_nontemporal_store(
                    v, reinterpret_cast<nfloat4*>(&outg[h * NCELL + o]));
            }
        }
    }
}

extern "C" void kernel_launch(void* const* d_in, const int* in_sizes, int n_in,
                              void* d_out, int out_size, void* d_ws, size_t ws_size,
                              hipStream_t stream)
{
    const int*   edge_index  = (const int*)d_in[0];
    const float* edge_w      = (const float*)d_in[1];
    const int E    = in_sizes[1];
    const int Ntot = in_sizes[2];
    const int G    = Ntot / NN;
    const int epg  = E / G;
    float* out = (float*)d_out;
    spb_fw_kernel<<<G, NT, 0, stream>>>(edge_index, edge_w, E, epg, out);
}

// Round 19
// 61.129 us; speedup vs baseline: 1.2885x; 1.2885x over previous
//
#include <hip/hip_runtime.h>

#define NHEADS 8
#define NN     128
#define NCELL  (NN * NN)       // 16384 floats = 64 KiB
#define NT     512             // 8 waves
#define SCALE_F 10.0f

typedef float nfloat4 __attribute__((ext_vector_type(4)));

// Blocked FW, B=16, one block (512 thr)/graph, f32 (the 61.3us trunk).
// Thread t: rgrp=t>>4 -> rows 4rgrp..+3 ; cgrp=t&15 -> cols 4cgrp+64c (c=0,1).
// dd[4][8] register-resident.
// Step kb (2 barriers):  B'(kb) ; bar ; C(kb) + extract(kb+1) + closure(kb+1)
//   [shadow wave kb+1 under s_setprio(1)] ; bar
//
// LDS float offsets:
#define RP_O 0        // [16][128] R_old
#define RP_N 2048     // [16][128] R_new
#define CP_As 4096    // [16][132] C_oldT parity 0
#define CP_Bs 6208    // parity 1
#define DPS  8320     // [16][20] diag tile / D*
#define RED  8640

template<int CBN>   // CBN = 4*(kbn>>2): dd column-half holding block kbn's cols
__device__ __forceinline__ void extract_panels(const float (&dd)[4][8], float* lds,
                                               const int kbn, const int t,
                                               const int rgrp, const int cgrp,
                                               const int cpbase)
{
    if ((rgrp >> 2) == kbn) {                 // wave kbn: row panel + diag
        const int q = rgrp & 3;
        #pragma unroll
        for (int rr = 0; rr < 4; ++rr) {
            const int iloc = 4 * q + rr;
            #pragma unroll
            for (int c = 0; c < 2; ++c) {
                *reinterpret_cast<float4*>(
                    &lds[RP_O + iloc * 128 + (cgrp << 2) + (c << 6)]) =
                    make_float4(dd[rr][c*4+0], dd[rr][c*4+1],
                                dd[rr][c*4+2], dd[rr][c*4+3]);
            }
        }
        const int p = cgrp - 4 * (kbn & 3);
        if ((unsigned)p < 4u) {
            #pragma unroll
            for (int rr = 0; rr < 4; ++rr) {
                *reinterpret_cast<float4*>(&lds[DPS + (4*q+rr) * 20 + (p << 2)]) =
                    make_float4(dd[rr][CBN+0], dd[rr][CBN+1],
                                dd[rr][CBN+2], dd[rr][CBN+3]);
            }
        }
    }
    {
        const int q2 = cgrp - 4 * (kbn & 3);   // col panel -> CPT[m][i]
        if ((unsigned)q2 < 4u) {
            #pragma unroll
            for (int e = 0; e < 4; ++e) {
                const int m = 4 * q2 + e;
                *reinterpret_cast<float4*>(&lds[cpbase + m * 132 + (rgrp << 2)]) =
                    make_float4(dd[0][CBN+e], dd[1][CBN+e],
                                dd[2][CBN+e], dd[3][CBN+e]);
            }
        }
    }
}

// wave kbn: f32 in-place shfl closure of DPS (in C's shadow; consumes its own
// wave's diag writes -> lgkmcnt(0) suffices).
__device__ __forceinline__ void closure(float* lds, const int t, const int kbn)
{
    if ((t >> 6) == kbn) {
        asm volatile("s_waitcnt lgkmcnt(0)" ::: "memory");
        const int l  = t & 63;
        const int i  = l & 15;
        const int jq = l >> 4;
        float4 v = *reinterpret_cast<const float4*>(&lds[DPS + i*20 + (jq << 2)]);
        float T0 = v.x, T1 = v.y, T2 = v.z, T3 = v.w;
        #pragma unroll
        for (int k = 0; k < 16; ++k) {
            const int ksrc = ((k >> 2) << 4) | i;
            float dik;
            switch (k & 3) {
                case 0: dik = __shfl(T0, ksrc); break;
                case 1: dik = __shfl(T1, ksrc); break;
                case 2: dik = __shfl(T2, ksrc); break;
                default: dik = __shfl(T3, ksrc); break;
            }
            const int rsrc = (jq << 4) | k;
            const float r0 = __shfl(T0, rsrc);
            const float r1 = __shfl(T1, rsrc);
            const float r2 = __shfl(T2, rsrc);
            const float r3 = __shfl(T3, rsrc);
            T0 = fminf(T0, dik + r0);
            T1 = fminf(T1, dik + r1);
            T2 = fminf(T2, dik + r2);
            T3 = fminf(T3, dik + r3);
        }
        *reinterpret_cast<float4*>(&lds[DPS + i*20 + (jq << 2)]) =
            make_float4(T0, T1, T2, T3);
    }
}

// B': R_new[r][j] = min_m D*[r][m] + R_old[m][j]; all 512 threads:
// r = t>>5, 4 cols at 4*(t&31). D* row r broadcast within half-wave.
__device__ __forceinline__ void bprime(float* lds, const int t)
{
    const float INF = __builtin_huge_valf();
    const int r  = t >> 5;
    const int j4 = (t & 31) << 2;
    float da[16];
    #pragma unroll
    for (int q = 0; q < 4; ++q) {
        float4 d4 = *reinterpret_cast<const float4*>(&lds[DPS + r*20 + (q << 2)]);
        da[4*q+0]=d4.x; da[4*q+1]=d4.y; da[4*q+2]=d4.z; da[4*q+3]=d4.w;
    }
    float a0 = INF, a1 = INF, a2 = INF, a3 = INF;
    #pragma unroll
    for (int m = 0; m < 16; ++m) {
        float4 rv = *reinterpret_cast<const float4*>(&lds[RP_O + m*128 + j4]);
        a0 = fminf(a0, da[m] + rv.x);
        a1 = fminf(a1, da[m] + rv.y);
        a2 = fminf(a2, da[m] + rv.z);
        a3 = fminf(a3, da[m] + rv.w);
    }
    *reinterpret_cast<float4*>(&lds[RP_N + r*128 + j4]) =
        make_float4(a0, a1, a2, a3);
}

// C: dd = min(dd, C_old[i][m] + R_new[m][j]) over 16 m.
__device__ __forceinline__ void cphase(float (&dd)[4][8], float* lds,
                                       const int rgrp, const int cgrp,
                                       const int cpbase)
{
    #pragma unroll
    for (int mq = 0; mq < 4; ++mq) {
        float4 cp[4], ra[4], rb[4];
        #pragma unroll
        for (int e = 0; e < 4; ++e) {
            const int m = 4*mq + e;
            cp[e] = *reinterpret_cast<const float4*>(&lds[cpbase + m*132 + (rgrp<<2)]);
            ra[e] = *reinterpret_cast<const float4*>(&lds[RP_N + m*128 + (cgrp<<2)]);
            rb[e] = *reinterpret_cast<const float4*>(&lds[RP_N + m*128 + (cgrp<<2) + 64]);
        }
        #pragma unroll
        for (int e2 = 0; e2 < 2; ++e2) {
            const float c0[4]  = {cp[2*e2].x, cp[2*e2].y, cp[2*e2].z, cp[2*e2].w};
            const float c1[4]  = {cp[2*e2+1].x, cp[2*e2+1].y, cp[2*e2+1].z, cp[2*e2+1].w};
            const float ra0[4] = {ra[2*e2].x, ra[2*e2].y, ra[2*e2].z, ra[2*e2].w};
            const float ra1[4] = {ra[2*e2+1].x, ra[2*e2+1].y, ra[2*e2+1].z, ra[2*e2+1].w};
            const float rb0[4] = {rb[2*e2].x, rb[2*e2].y, rb[2*e2].z, rb[2*e2].w};
            const float rb1[4] = {rb[2*e2+1].x, rb[2*e2+1].y, rb[2*e2+1].z, rb[2*e2+1].w};
            #pragma unroll
            for (int rr = 0; rr < 4; ++rr) {
                #pragma unroll
                for (int e = 0; e < 4; ++e) {
                    dd[rr][e]   = fminf(fminf(dd[rr][e],   c0[rr] + ra0[e]), c1[rr] + ra1[e]);
                    dd[rr][4+e] = fminf(fminf(dd[rr][4+e], c0[rr] + rb0[e]), c1[rr] + rb1[e]);
                }
            }
        }
    }
}

__global__ __launch_bounds__(NT, 2)
void spb_fw_kernel(const int* __restrict__ edge_index,
                   const float* __restrict__ edge_weight,
                   const int num_edges, const int epg,
                   float* __restrict__ out)
{
    __shared__ float lds[NCELL];
    const float INF = __builtin_huge_valf();
    const int t    = threadIdx.x;
    const int g    = blockIdx.x;
    const int cgrp = t & 15;
    const int rgrp = t >> 4;

    // ---- prefetch edges (4/thread, clamped; dup scatter idempotent) ----
    const int ebase = g * epg;
    int esrc[4], edst[4]; float ew[4];
    #pragma unroll
    for (int k = 0; k < 4; ++k) {
        int e = t + k * NT;
        e = (e < epg) ? e : (epg - 1);
        const int idx = ebase + e;
        esrc[k] = edge_index[idx];
        edst[k] = edge_index[num_edges + idx];
        ew[k]   = edge_weight[idx];
    }

    // ---- init matrix (swizzled: elem(i,col) at i*128 + (col ^ ((i&7)<<2))) ----
    #pragma unroll
    for (int c = 0; c < 8; ++c) {
        const int m   = t + (c << 9);
        const int i   = m >> 5;
        const int scm = m & 31;
        const int c0  = (scm ^ (i & 7)) << 2;
        float4 v;
        v.x = (c0 + 0 == i) ? 0.0f : INF;
        v.y = (c0 + 1 == i) ? 0.0f : INF;
        v.z = (c0 + 2 == i) ? 0.0f : INF;
        v.w = (c0 + 3 == i) ? 0.0f : INF;
        *reinterpret_cast<float4*>(&lds[m << 2]) = v;
    }
    __syncthreads();

    // ---- scatter edges (atomicMin on int view of positive floats) ----
    #pragma unroll
    for (int k = 0; k < 4; ++k) {
        const int u = esrc[k] - g * NN;
        const int v = edst[k] - g * NN;
        if (u != v && (unsigned)u < (unsigned)NN && (unsigned)v < (unsigned)NN) {
            const int a = (u << 7) + (v ^ ((u & 7) << 2));
            atomicMin(reinterpret_cast<int*>(&lds[a]), __float_as_int(ew[k]));
        }
    }
    __syncthreads();

    // ---- load dd: dd[rr][c*4+e] = d[4rgrp+rr][4cgrp+64c+e] ----
    float dd[4][8];
    #pragma unroll
    for (int rr = 0; rr < 4; ++rr) {
        const int i = (rgrp << 2) + rr;
        const int s = i & 7;
        #pragma unroll
        for (int c = 0; c < 2; ++c) {
            float4 v = *reinterpret_cast<const float4*>(
                &lds[(i << 7) + (((cgrp + 16*c) ^ s) << 2)]);
            dd[rr][c*4+0]=v.x; dd[rr][c*4+1]=v.y; dd[rr][c*4+2]=v.z; dd[rr][c*4+3]=v.w;
        }
    }
    __syncthreads();   // matrix region dead; panels may be written

    // ---- prologue: extract(0) + closure(0) in wave 0's shadow ----
    extract_panels<0>(dd, lds, 0, t, rgrp, cgrp, CP_As);
    closure(lds, t, 0);
    __syncthreads();

    // ---- blocked FW: 8 steps, 2 barriers each (ROLLED) ----
    #pragma unroll 1
    for (int kb = 0; kb < 8; ++kb) {
        bprime(lds, t);
        __syncthreads();
        const int kbn = kb + 1;
        const bool shadow = (kb < 7) && ((t >> 6) == kbn);
        if (shadow) __builtin_amdgcn_s_setprio(1);   // critical-chain wave
        cphase(dd, lds, rgrp, cgrp, (kb & 1) ? CP_Bs : CP_As);
        if (kb < 7) {
            const int cpb = (kbn & 1) ? CP_Bs : CP_As;
            if (kbn < 4) extract_panels<0>(dd, lds, kbn, t, rgrp, cgrp, cpb);
            else         extract_panels<4>(dd, lds, kbn, t, rgrp, cgrp, cpb);
            closure(lds, t, kbn);    // wave kbn only, intra-wave, in C's shadow
        }
        if (shadow) __builtin_amdgcn_s_setprio(0);
        __syncthreads();
    }

    // ---- reductions (max finite, global max) ----
    float mF = 0.0f, mA = 0.0f;
    #pragma unroll
    for (int rr = 0; rr < 4; ++rr)
        #pragma unroll
        for (int j = 0; j < 8; ++j) {
            const float v = dd[rr][j];
            mA = fmaxf(mA, v);
            mF = fmaxf(mF, v < INF ? v : 0.0f);
        }
    #pragma unroll
    for (int o = 32; o > 0; o >>= 1) {
        mF = fmaxf(mF, __shfl_xor(mF, o));
        mA = fmaxf(mA, __shfl_xor(mA, o));
    }
    if ((t & 63) == 0) {
        lds[RED + ((t >> 6) << 1)]     = mF;
        lds[RED + ((t >> 6) << 1) + 1] = mA;
    }
    __syncthreads();
    mF = lds[RED]; mA = lds[RED + 1];
    #pragma unroll
    for (int wv = 1; wv < 8; ++wv) {
        mF = fmaxf(mF, lds[RED + wv*2]);
        mA = fmaxf(mA, lds[RED + wv*2 + 1]);
    }
    const float twoF  = 2.0f * mF;
    const float maxv  = fmaxf((mA == INF) ? twoF : mF, 1e-8f);
    const float nscal = -SCALE_F / maxv;

    // ---- normalize in registers, store 8 heads (coalesced, nontemporal) ----
    float* const outg = out + (size_t)g * (NHEADS * NCELL);
    #pragma unroll
    for (int rr = 0; rr < 4; ++rr) {
        const int i = (rgrp << 2) + rr;
        #pragma unroll
        for (int c = 0; c < 2; ++c) {
            nfloat4 v;
            v.x = ((dd[rr][c*4+0] == INF) ? twoF : dd[rr][c*4+0]) * nscal;
            v.y = ((dd[rr][c*4+1] == INF) ? twoF : dd[rr][c*4+1]) * nscal;
            v.z = ((dd[rr][c*4+2] == INF) ? twoF : dd[rr][c*4+2]) * nscal;
            v.w = ((dd[rr][c*4+3] == INF) ? twoF : dd[rr][c*4+3]) * nscal;
            const int o = (i << 7) + (cgrp << 2) + (c << 6);
            #pragma unroll
            for (int h = 0; h < NHEADS; ++h) {
                __builtin_nontemporal_store(
                    v, reinterpret_cast<nfloat4*>(&outg[h * NCELL + o]));
            }
        }
    }
}

extern "C" void kernel_launch(void* const* d_in, const int* in_sizes, int n_in,
                              void* d_out, int out_size, void* d_ws, size_t ws_size,
                              hipStream_t stream)
{
    const int*   edge_index  = (const int*)d_in[0];
    const float* edge_w      = (const float*)d_in[1];
    const int E    = in_sizes[1];
    const int Ntot = in_sizes[2];
    const int G    = Ntot / NN;
    const int epg  = E / G;
    float* out = (float*)d_out;
    spb_fw_kernel<<<G, NT, 0, stream>>>(edge_index, edge_w, E, epg, out);
}